// Round 12
// baseline (192.632 us; speedup 1.0000x reference)
//
#include <hip/hip_runtime.h>

// Classwise circular-buffer queue update — SPLIT-STREAM variant.
// occ_i = rank of proposal i within its class; slot = (tail[l]+occ)%Q;
// final writer iff occ >= k_l - Q.  Writer map is injective =>
//   tgt[i]  = destination row for qualifying proposal i  (else -1)
//   idx[row] >= 0 marks rows sourced from feat
// Pass A (k_scatter): sequential feat read, scattered 1KB row writes.
// Pass B (k_copy):    sequential queue read/write, skipping written rows.
// NOTE (r9): cooperative grid.sync ~100us on MI355X — separate launches
// are the cheap grid barrier.  (r7/r4): MLP-deepening regresses; one wave
// per 1KB row is the best copy structure.  (r11): NT loads+stores pay on
// single-use streams.

typedef float vf4 __attribute__((ext_vector_type(4)));
typedef int   vi4 __attribute__((ext_vector_type(4)));

#define HBLK 1024  // proposals per histogram chunk (cnt row granularity)

// Full-occupancy workspace init: idx = -1, tgt = -1, cnt = 0.
__global__ void k_zero(int* __restrict__ idx, long long nIdx,
                       int* __restrict__ tgt, long long nTgt,
                       int* __restrict__ cnt, long long nCnt) {
    long long stride = (long long)gridDim.x * blockDim.x;
    long long g0 = (long long)blockIdx.x * blockDim.x + threadIdx.x;
    vi4* idx4 = (vi4*)idx;
    vi4* tgt4 = (vi4*)tgt;
    vi4* cnt4 = (vi4*)cnt;
    vi4 mone; mone.x = mone.y = mone.z = mone.w = -1;
    vi4 zero; zero.x = zero.y = zero.z = zero.w = 0;
    long long n4i = nIdx >> 2, n4t = nTgt >> 2, n4c = nCnt >> 2;
    for (long long g = g0; g < n4i; g += stride) idx4[g] = mone;
    for (long long g = g0; g < n4t; g += stride) tgt4[g] = mone;
    for (long long g = g0; g < n4c; g += stride) cnt4[g] = zero;
    if (g0 < (nIdx & 3)) idx[n4i * 4 + g0] = -1;
    if (g0 < (nTgt & 3)) tgt[n4t * 4 + g0] = -1;
    if (g0 < (nCnt & 3)) cnt[n4c * 4 + g0] = 0;
}

// Pure-atomic chunk histogram: cnt[(i/HBLK)*C + l]++.
__global__ void k_hist(const int* __restrict__ lab, int* __restrict__ cnt,
                       int N, int C) {
    int i = blockIdx.x * blockDim.x + threadIdx.x;
    if (i < N) {
        int l = lab[i];
        if (l >= 0 && l < C) atomicAdd(&cnt[(size_t)(i >> 10) * C + l], 1);
    }
}

// Column-wise exclusive prefix over chunks; total per label.
__global__ void k_prefix(int* __restrict__ cnt, int* __restrict__ ktot,
                         int C, int NB) {
    int l = blockIdx.x * blockDim.x + threadIdx.x;
    if (l >= C) return;
    int run = 0;
    for (int b = 0; b < NB; ++b) {
        int t = cnt[(size_t)b * C + l];
        cnt[(size_t)b * C + l] = run;  // exclusive prefix per (chunk,label)
        run += t;
    }
    ktot[l] = run;                     // total count per label
}

__global__ void k_slots(const int* __restrict__ lab, const int* __restrict__ tail,
                        const int* __restrict__ cnt, const int* __restrict__ ktot,
                        int* __restrict__ idx, int* __restrict__ tgt,
                        int N, int C, int Q) {
    __shared__ __align__(16) int slab[HBLK];
    int b = blockIdx.x;
    int t = threadIdx.x;
    int i = b * HBLK + t;
    int l = (i < N) ? lab[i] : -1;
    slab[t] = l;
    __syncthreads();
    if (l < 0 || l >= C) return;
    // local rank within chunk: count slab[j]==l for j<t, 4 labels/iter
    const vi4* slab4 = (const vi4*)slab;
    int local = 0;
    int nw = t >> 2;
    for (int w = 0; w < nw; ++w) {
        vi4 v = slab4[w];  // broadcast ds_read_b128
        local += (v.x == l) + (v.y == l) + (v.z == l) + (v.w == l);
    }
    for (int j = t & ~3; j < t; ++j) local += (slab[j] == l);
    int occ = cnt[(size_t)b * C + l] + local;
    int kk = ktot[l];
    if (occ >= kk - Q) {
        int s = (tail[l] + occ) % Q;
        if (s < 0) s += Q;            // python-style mod (positive divisor)
        int row = l * Q + s;
        idx[row] = i;                 // row is feat-sourced
        tgt[i] = row;                 // inverse map for sequential-read scatter
    }
}

// Pass A (F==256): wave per proposal row; sequential feat read (NT),
// scattered 1KB row write (NT).  tgt load scalar.
__global__ void __launch_bounds__(256) k_scatter(
        const vf4* __restrict__ feat, const int* __restrict__ tgt,
        vf4* __restrict__ out, int N) {
    int wave = threadIdx.x >> 6;
    int lane = threadIdx.x & 63;
    int i = __builtin_amdgcn_readfirstlane(blockIdx.x * 4 + wave);
    if (i >= N) return;
    int row = tgt[i];  // scalar, wave-uniform
    if (row < 0) return;
    vf4 v = __builtin_nontemporal_load(feat + ((size_t)i << 6) + lane);
    __builtin_nontemporal_store(v, out + ((size_t)row << 6) + lane);
}

// Pass B (F==256): wave per output row; sequential queue read/write with
// holes (skip feat-sourced rows).  idx load scalar.
__global__ void __launch_bounds__(256) k_copy(
        const vf4* __restrict__ queue, const int* __restrict__ idx,
        vf4* __restrict__ out, int R) {
    int wave = threadIdx.x >> 6;
    int lane = threadIdx.x & 63;
    int r = __builtin_amdgcn_readfirstlane(blockIdx.x * 4 + wave);
    if (r >= R) return;
    if (idx[r] >= 0) return;  // feat-sourced: written by k_scatter
    vf4 v = __builtin_nontemporal_load(queue + ((size_t)r << 6) + lane);
    __builtin_nontemporal_store(v, out + ((size_t)r << 6) + lane);
}

// Generic fallback (any F divisible by 4): single-pass gather via idx.
__global__ void k_gather_g(const vf4* __restrict__ feat,
                           const vf4* __restrict__ queue,
                           const int* __restrict__ idx,
                           vf4* __restrict__ out,
                           long long total4, int F4) {
    long long stride = (long long)gridDim.x * blockDim.x;
    for (long long g = (long long)blockIdx.x * blockDim.x + threadIdx.x;
         g < total4; g += stride) {
        int r = (int)(g / F4);
        int c = (int)(g - (long long)r * F4);
        int id = idx[r];
        const vf4* src = (id >= 0) ? (feat + (size_t)id * F4 + c)
                                   : (queue + (size_t)r * F4 + c);
        vf4 v = __builtin_nontemporal_load(src);
        __builtin_nontemporal_store(v, &out[g]);
    }
}

extern "C" void kernel_launch(void* const* d_in, const int* in_sizes, int n_in,
                              void* d_out, int out_size, void* d_ws, size_t ws_size,
                              hipStream_t stream) {
    const float* feat  = (const float*)d_in[0];
    const float* queue = (const float*)d_in[1];
    const int*   lab   = (const int*)d_in[2];
    const int*   tail  = (const int*)d_in[3];

    const int N = in_sizes[2];
    const int C = in_sizes[3];
    const int F = in_sizes[0] / N;
    const int Q = in_sizes[1] / (C * F);
    const int NB = (N + HBLK - 1) / HBLK;

    int* idx  = (int*)d_ws;                    // C*Q
    int* cnt  = idx + (size_t)C * Q;           // NB*C
    int* ktot = cnt + (size_t)NB * C;          // C
    int* tgt  = ktot + C;                      // N

    const long long R = (long long)C * Q;
    k_zero<<<2048, 256, 0, stream>>>(idx, R, tgt, (long long)N,
                                     cnt, (long long)NB * C);
    k_hist<<<(N + 255) / 256, 256, 0, stream>>>(lab, cnt, N, C);
    k_prefix<<<(C + 255) / 256, 256, 0, stream>>>(cnt, ktot, C, NB);
    k_slots<<<NB, HBLK, 0, stream>>>(lab, tail, cnt, ktot, idx, tgt, N, C, Q);

    if (F == 256) {
        k_scatter<<<(N + 3) / 4, 256, 0, stream>>>((const vf4*)feat, tgt,
                                                   (vf4*)d_out, N);
        k_copy<<<(int)((R + 3) / 4), 256, 0, stream>>>((const vf4*)queue, idx,
                                                       (vf4*)d_out, (int)R);
    } else {
        const int F4 = F / 4;
        const long long total4 = R * F4;
        int gblocks = 2048;
        long long need = (total4 + 255) / 256;
        if (need < gblocks) gblocks = (int)need;
        k_gather_g<<<gblocks, 256, 0, stream>>>((const vf4*)feat,
                                                (const vf4*)queue, idx,
                                                (vf4*)d_out, total4, F4);
    }
}

// Round 13
// 175.114 us; speedup vs baseline: 1.1000x; 1.1000x over previous
//
#include <hip/hip_runtime.h>

// Classwise circular-buffer queue update.
// occ_i = rank of proposal i within its class (original index order).
// slot  = (tail[l] + occ) % Q.  Proposal i is the FINAL writer of its slot
// iff occ >= k_l - Q (last min(k,Q) ranks cover distinct slots exactly once).
// => conflict-free scatter of proposal index into idx[C*Q], then one
// streaming gather pass building the output.
// NOTE (r9): cooperative-kernel fusion of the aux phases is a disaster on
// MI355X — grid.sync() ~100us each (device-scope fence across 8 non-coherent
// XCD L2s). Separate launches are the cheap grid barrier.
// NOTE (r7/r4): gather MLP-deepening (4 rows/wave, LDS tiling) regresses;
// one wave per 1KB row, direct-mapped, is the best structure found.
// NOTE (r12): splitting the gather into sequential-feat-scatter + queue-copy
// passes regresses (random 1KB writes cost the same as random reads, plus
// extra pass overhead). Single-pass mixed-pattern gather at ~5.0 TB/s
// effective is the DRAM bound for this access mixture.

typedef float vf4 __attribute__((ext_vector_type(4)));
typedef int   vi4 __attribute__((ext_vector_type(4)));

#define HBLK 1024  // proposals per histogram chunk (cnt row granularity)

// Full-occupancy workspace init: idx = -1, cnt = 0.  Vectorized grid-stride.
__global__ void k_zero(int* __restrict__ idx, long long nIdx,
                       int* __restrict__ cnt, long long nCnt) {
    long long stride = (long long)gridDim.x * blockDim.x;
    long long g0 = (long long)blockIdx.x * blockDim.x + threadIdx.x;
    vi4* idx4 = (vi4*)idx;
    vi4* cnt4 = (vi4*)cnt;
    vi4 mone; mone.x = mone.y = mone.z = mone.w = -1;
    vi4 zero; zero.x = zero.y = zero.z = zero.w = 0;
    long long n4i = nIdx >> 2, n4c = nCnt >> 2;
    for (long long g = g0; g < n4i; g += stride) idx4[g] = mone;
    for (long long g = g0; g < n4c; g += stride) cnt4[g] = zero;
    if (g0 < (nIdx & 3)) idx[n4i * 4 + g0] = -1;
    if (g0 < (nCnt & 3)) cnt[n4c * 4 + g0] = 0;
}

// Pure-atomic chunk histogram: cnt[(i/HBLK)*C + l]++.  High occupancy.
__global__ void k_hist(const int* __restrict__ lab, int* __restrict__ cnt,
                       int N, int C) {
    int i = blockIdx.x * blockDim.x + threadIdx.x;
    if (i < N) {
        int l = lab[i];
        if (l >= 0 && l < C) atomicAdd(&cnt[(size_t)(i >> 10) * C + l], 1);
    }
}

// Column-wise exclusive prefix over chunks; total per label.
__global__ void k_prefix(int* __restrict__ cnt, int* __restrict__ ktot,
                         int C, int NB) {
    int l = blockIdx.x * blockDim.x + threadIdx.x;
    if (l >= C) return;
    int run = 0;
    for (int b = 0; b < NB; ++b) {
        int t = cnt[(size_t)b * C + l];
        cnt[(size_t)b * C + l] = run;  // exclusive prefix per (chunk,label)
        run += t;
    }
    ktot[l] = run;                     // total count per label
}

__global__ void k_slots(const int* __restrict__ lab, const int* __restrict__ tail,
                        const int* __restrict__ cnt, const int* __restrict__ ktot,
                        int* __restrict__ idx, int N, int C, int Q) {
    __shared__ __align__(16) int slab[HBLK];
    int b = blockIdx.x;
    int t = threadIdx.x;
    int i = b * HBLK + t;
    int l = (i < N) ? lab[i] : -1;
    slab[t] = l;
    __syncthreads();
    if (l < 0 || l >= C) return;
    // local rank within chunk: count slab[j]==l for j<t, 4 labels/iter
    const vi4* slab4 = (const vi4*)slab;
    int local = 0;
    int nw = t >> 2;
    for (int w = 0; w < nw; ++w) {
        vi4 v = slab4[w];  // broadcast ds_read_b128
        local += (v.x == l) + (v.y == l) + (v.z == l) + (v.w == l);
    }
    for (int j = t & ~3; j < t; ++j) local += (slab[j] == l);
    int occ = cnt[(size_t)b * C + l] + local;
    int kk = ktot[l];
    if (occ >= kk - Q) {
        int s = (tail[l] + occ) % Q;
        if (s < 0) s += Q;            // python-style mod (positive divisor)
        idx[l * Q + s] = i;           // unique (class,slot) per qualifier
    }
}

// Direct-mapped gather (F==256): 256-thread block = 4 waves, one wave per
// 1KB row.  idx load scalar (readfirstlane -> s_load via K$); data loads
// NON-TEMPORAL (all reads single-use -> bypass L2 retention); NT store.
__global__ void __launch_bounds__(256) k_gather_d(
        const vf4* __restrict__ feat, const vf4* __restrict__ queue,
        const int* __restrict__ idx, vf4* __restrict__ out, int R) {
    int wave = threadIdx.x >> 6;
    int lane = threadIdx.x & 63;
    int r = __builtin_amdgcn_readfirstlane(blockIdx.x * 4 + wave);
    if (r >= R) return;
    int id = idx[r];  // scalar load, wave-uniform
    const vf4* src = (id >= 0) ? (feat + ((size_t)id << 6) + lane)
                               : (queue + ((size_t)r << 6) + lane);
    vf4 v = __builtin_nontemporal_load(src);
    __builtin_nontemporal_store(v, out + ((size_t)r << 6) + lane);
}

// Generic fallback (any F divisible by 4).
__global__ void k_gather_g(const vf4* __restrict__ feat,
                           const vf4* __restrict__ queue,
                           const int* __restrict__ idx,
                           vf4* __restrict__ out,
                           long long total4, int F4) {
    long long stride = (long long)gridDim.x * blockDim.x;
    for (long long g = (long long)blockIdx.x * blockDim.x + threadIdx.x;
         g < total4; g += stride) {
        int r = (int)(g / F4);
        int c = (int)(g - (long long)r * F4);
        int id = idx[r];
        const vf4* src = (id >= 0) ? (feat + (size_t)id * F4 + c)
                                   : (queue + (size_t)r * F4 + c);
        vf4 v = __builtin_nontemporal_load(src);
        __builtin_nontemporal_store(v, &out[g]);
    }
}

extern "C" void kernel_launch(void* const* d_in, const int* in_sizes, int n_in,
                              void* d_out, int out_size, void* d_ws, size_t ws_size,
                              hipStream_t stream) {
    const float* feat  = (const float*)d_in[0];
    const float* queue = (const float*)d_in[1];
    const int*   lab   = (const int*)d_in[2];
    const int*   tail  = (const int*)d_in[3];

    const int N = in_sizes[2];
    const int C = in_sizes[3];
    const int F = in_sizes[0] / N;
    const int Q = in_sizes[1] / (C * F);
    const int NB = (N + HBLK - 1) / HBLK;

    int* idx  = (int*)d_ws;                    // C*Q
    int* cnt  = idx + (size_t)C * Q;           // NB*C
    int* ktot = cnt + (size_t)NB * C;          // C

    const long long R = (long long)C * Q;
    k_zero<<<2048, 256, 0, stream>>>(idx, R, cnt, (long long)NB * C);
    k_hist<<<(N + 255) / 256, 256, 0, stream>>>(lab, cnt, N, C);
    k_prefix<<<(C + 255) / 256, 256, 0, stream>>>(cnt, ktot, C, NB);
    k_slots<<<NB, HBLK, 0, stream>>>(lab, tail, cnt, ktot, idx, N, C, Q);

    const int F4 = F / 4;
    const long long total4 = R * F4;
    if (F == 256) {
        const int blocks = (int)((R + 3) / 4);   // 4 rows per 256-thread block
        k_gather_d<<<blocks, 256, 0, stream>>>((const vf4*)feat,
                                               (const vf4*)queue, idx,
                                               (vf4*)d_out, (int)R);
    } else {
        int gblocks = 2048;
        long long need = (total4 + 255) / 256;
        if (need < gblocks) gblocks = (int)need;
        k_gather_g<<<gblocks, 256, 0, stream>>>((const vf4*)feat,
                                                (const vf4*)queue, idx,
                                                (vf4*)d_out, total4, F4);
    }
}